// Round 8
// baseline (245.446 us; speedup 1.0000x reference)
//
#include <hip/hip_runtime.h>
#include <hip/hip_bf16.h>
#include <cstdint>
#include <cstddef>

// Problem constants
constexpr int Bc  = 4;
constexpr int Tc  = 2048;
constexpr int Dc  = 1024;
constexpr int Hc  = 16;
constexpr int DHc = 64;
constexpr int T2c = 1024;
constexpr int NCc = 32;          // chunks per (b,h) row; chunk = 64 timesteps
constexpr int NEXT = 1152;       // extended N for v-GEMM: 1024 v + 16 scores + 112 pad
#define LN_EPS_F 1e-5f

typedef __attribute__((ext_vector_type(8))) short bf16x8;
typedef __attribute__((ext_vector_type(8))) ushort ushort8_t;
typedef __attribute__((ext_vector_type(4))) float f32x4;

__device__ inline ushort f2bf(float f) {
    union { float f; uint32_t u; } v; v.f = f;
    uint32_t r = v.u + 0x7FFFu + ((v.u >> 16) & 1u);   // RNE
    return (ushort)(r >> 16);
}
__device__ inline float bf2f(ushort u) {
    union { uint32_t u; float f; } v; v.u = ((uint32_t)u) << 16;
    return v.f;
}

// ---------------------------------------------------------------------------
// K0: fused prep (grid-partitioned):
//   [0, 8192)        x fp32 -> xb bf16 (float4 loads)
//   [8192, 9216)     Wv [1024][1024] -> WvXT rows 0..1023   ([n][k] bf16)
//   [9216, 9728)     Wt [1024][512]  -> WtT  [512][1024]
//   [9728, 9792)     qk fold -> WvXT rows 1024..1039  (scale 1/8 folded)
//   [9792, 9848)     zero WvXT rows 1040..1151
// ---------------------------------------------------------------------------
constexpr int PREP_CVT  = 8192;
constexpr int PREP_WV   = PREP_CVT + 1024;
constexpr int PREP_WT   = PREP_WV + 512;
constexpr int PREP_QK   = PREP_WT + 64;
constexpr int PREP_ZERO = PREP_QK + 56;

__global__ __launch_bounds__(256) void k_prep(const float* __restrict__ x,
                                              const float* __restrict__ Wv,
                                              const float* __restrict__ Wt,
                                              const float* __restrict__ Wk,
                                              const float* __restrict__ query,
                                              ushort* __restrict__ xb,
                                              ushort* __restrict__ WvXT,
                                              ushort* __restrict__ WtT) {
    __shared__ float tile[32][33];
    int blk = blockIdx.x;
    int tid = threadIdx.x;
    if (blk < PREP_CVT) {
        int i = (blk * 256 + tid) * 4;
        float4 f = *(const float4*)(x + i);
        ushort4 o;
        o.x = f2bf(f.x); o.y = f2bf(f.y); o.z = f2bf(f.z); o.w = f2bf(f.w);
        *(ushort4*)(xb + i) = o;
    } else if (blk < PREP_WV) {
        int b2 = blk - PREP_CVT;
        int bx = b2 & 31, by = b2 >> 5;              // n-tile, k-tile
        int tx = tid & 31, ty = tid >> 5;
        #pragma unroll
        for (int r = 0; r < 32; r += 8)
            tile[ty + r][tx] = Wv[(size_t)(by * 32 + ty + r) * Dc + bx * 32 + tx];
        __syncthreads();
        #pragma unroll
        for (int r = 0; r < 32; r += 8)
            WvXT[(size_t)(bx * 32 + ty + r) * Dc + by * 32 + tx] = f2bf(tile[tx][ty + r]);
    } else if (blk < PREP_WT) {
        int b2 = blk - PREP_WV;
        int bx = b2 & 15, by = b2 >> 4;              // n-tile (512), k-tile (1024)
        int tx = tid & 31, ty = tid >> 5;
        #pragma unroll
        for (int r = 0; r < 32; r += 8)
            tile[ty + r][tx] = Wt[(size_t)(by * 32 + ty + r) * (Dc / 2) + bx * 32 + tx];
        __syncthreads();
        #pragma unroll
        for (int r = 0; r < 32; r += 8)
            WtT[(size_t)(bx * 32 + ty + r) * Dc + by * 32 + tx] = f2bf(tile[tx][ty + r]);
    } else if (blk < PREP_QK) {
        int idx = (blk - PREP_WT) * 256 + tid;       // 0..16383
        int h = idx >> 10, i = idx & (Dc - 1);
        const float* wrow = Wk + (size_t)i * Dc + h * DHc;
        const float* qh   = query + h * DHc;
        float s = 0.f;
        #pragma unroll 8
        for (int d = 0; d < DHc; ++d) s += wrow[d] * qh[d];
        WvXT[(size_t)(Dc + h) * Dc + i] = f2bf(s * 0.125f);
    } else {
        int idx = (blk - PREP_QK) * 256 + tid;       // 0..14335 -> 8 ushorts each
        uint4 z = {0, 0, 0, 0};
        *(uint4*)(WvXT + (size_t)1040 * Dc + idx * 8) = z;
    }
}

// ---------------------------------------------------------------------------
// K4a: v-GEMM + scores, DIRECT-GLOBAL MFMA (no LDS, no barriers).
//   One wave per 64x64 tile. grid = (M/64 fastest for XCD, N64 tiles).
//   A,B frags are 16B/lane global loads; compiler keeps 8-16 in flight.
//   cols < 1024 -> v (bf16); 1024..1039 -> scores fp32 (transposed); rest drop.
// ---------------------------------------------------------------------------
__global__ __launch_bounds__(64) void k_gemm_v(const ushort* __restrict__ A,
                                               const ushort* __restrict__ Bt,
                                               ushort* __restrict__ v,
                                               float* __restrict__ scores) {
    constexpr int K = Dc;
    int lane = threadIdx.x;
    int l15 = lane & 15, quad = lane >> 4;
    int tile_m = blockIdx.x * 64, tile_n = blockIdx.y * 64;   // row fastest (XCD)

    f32x4 acc[4][4] = {};
    const ushort* arow = A  + (size_t)(tile_m + l15) * K + quad * 8;
    const ushort* brow = Bt + (size_t)(tile_n + l15) * K + quad * 8;

    #pragma unroll 2
    for (int k0 = 0; k0 < K; k0 += 32) {
        bf16x8 a[4], b[4];
        #pragma unroll
        for (int i = 0; i < 4; ++i)
            a[i] = *(const bf16x8*)(arow + (size_t)i * 16 * K + k0);
        #pragma unroll
        for (int j = 0; j < 4; ++j)
            b[j] = *(const bf16x8*)(brow + (size_t)j * 16 * K + k0);
        #pragma unroll
        for (int i = 0; i < 4; ++i)
            #pragma unroll
            for (int j = 0; j < 4; ++j)
                acc[i][j] = __builtin_amdgcn_mfma_f32_16x16x32_bf16(a[i], b[j], acc[i][j], 0, 0, 0);
    }

    // epilogue: C/D mapping col=lane&15, row=quad*4+reg
    #pragma unroll
    for (int j = 0; j < 4; ++j) {
        int col = tile_n + j * 16 + l15;
        #pragma unroll
        for (int i = 0; i < 4; ++i) {
            #pragma unroll
            for (int r = 0; r < 4; ++r) {
                int row = tile_m + i * 16 + quad * 4 + r;
                float val = acc[i][j][r];
                if (col < Dc) {
                    v[(size_t)row * Dc + col] = f2bf(val);
                } else if (col < Dc + Hc) {
                    int h = col - Dc;
                    int b2 = row >> 11, t = row & (Tc - 1);
                    scores[((size_t)b2 * Hc + h) * Tc + t] = val;
                }
            }
        }
    }
}

// ---------------------------------------------------------------------------
// K4b: generic direct-global MFMA GEMM (theta). One wave per 64x64 tile.
// ---------------------------------------------------------------------------
__global__ __launch_bounds__(64) void k_gemm_t(const ushort* __restrict__ A,
                                               const ushort* __restrict__ Bt,
                                               const float* __restrict__ bias,
                                               float* __restrict__ C,
                                               int N, int K) {
    int lane = threadIdx.x;
    int l15 = lane & 15, quad = lane >> 4;
    int tile_m = blockIdx.x * 64, tile_n = blockIdx.y * 64;   // row fastest (XCD)

    f32x4 acc[4][4] = {};
    const ushort* arow = A  + (size_t)(tile_m + l15) * K + quad * 8;
    const ushort* brow = Bt + (size_t)(tile_n + l15) * K + quad * 8;

    #pragma unroll 2
    for (int k0 = 0; k0 < K; k0 += 32) {
        bf16x8 a[4], b[4];
        #pragma unroll
        for (int i = 0; i < 4; ++i)
            a[i] = *(const bf16x8*)(arow + (size_t)i * 16 * K + k0);
        #pragma unroll
        for (int j = 0; j < 4; ++j)
            b[j] = *(const bf16x8*)(brow + (size_t)j * 16 * K + k0);
        #pragma unroll
        for (int i = 0; i < 4; ++i)
            #pragma unroll
            for (int j = 0; j < 4; ++j)
                acc[i][j] = __builtin_amdgcn_mfma_f32_16x16x32_bf16(a[i], b[j], acc[i][j], 0, 0, 0);
    }

    #pragma unroll
    for (int j = 0; j < 4; ++j) {
        int col = tile_n + j * 16 + l15;
        float bv = bias[col];
        #pragma unroll
        for (int i = 0; i < 4; ++i) {
            #pragma unroll
            for (int r = 0; r < 4; ++r) {
                int row = tile_m + i * 16 + quad * 4 + r;
                C[(size_t)row * N + col] = acc[i][j][r] + bv;
            }
        }
    }
}

// ---------------------------------------------------------------------------
// K5a: per-chunk totals of E_t and E_t * v[t,h,:]  (shift-free softmax)
// ---------------------------------------------------------------------------
__global__ __launch_bounds__(64) void k_chunk(const float* __restrict__ scores,
                                              const ushort* __restrict__ v,
                                              float* __restrict__ chunkL,
                                              float* __restrict__ chunkAcc) {
    int idx = blockIdx.x;
    int c = idx & (NCc - 1);
    int bh = idx / NCc;
    int h = bh & (Hc - 1), b = bh / Hc;
    int lane = threadIdx.x;
    int tgrp = lane >> 3;
    int dgrp = lane & 7;
    int t0 = c * 64;
    const float* srow = scores + (size_t)bh * Tc + t0;
    const ushort* vbase = v + ((size_t)b * Tc + t0) * Dc + h * DHc + dgrp * 8;
    float acc[8] = {};
    float lsum = 0.f;
    #pragma unroll
    for (int it = 0; it < 8; ++it) {
        int t = it * 8 + tgrp;
        float e = expf(srow[t]);
        ushort8_t vv = *(const ushort8_t*)(vbase + (size_t)t * Dc);
        #pragma unroll
        for (int k = 0; k < 8; ++k) acc[k] += e * bf2f(vv[k]);
        lsum += e;
    }
    #pragma unroll
    for (int m = 8; m < 64; m <<= 1) {
        #pragma unroll
        for (int k = 0; k < 8; ++k) acc[k] += __shfl_xor(acc[k], m);
        lsum += __shfl_xor(lsum, m);
    }
    if (tgrp == 0) {
        float4 lo = {acc[0], acc[1], acc[2], acc[3]};
        float4 hi = {acc[4], acc[5], acc[6], acc[7]};
        *(float4*)&chunkAcc[(size_t)idx * DHc + dgrp * 8]     = lo;
        *(float4*)&chunkAcc[(size_t)idx * DHc + dgrp * 8 + 4] = hi;
        if (dgrp == 0) chunkL[idx] = lsum;
    }
}

// ---------------------------------------------------------------------------
// K5c: within-chunk scan + emit (prefix over prior chunks computed inline)
// ---------------------------------------------------------------------------
__global__ __launch_bounds__(64) void k_emit(const float* __restrict__ scores,
                                             const ushort* __restrict__ v,
                                             const float* __restrict__ chunkL,
                                             const float* __restrict__ chunkAcc,
                                             ushort* __restrict__ pooled) {
    int idx = blockIdx.x;
    int c = idx & (NCc - 1);
    int bh = idx / NCc;
    int h = bh & (Hc - 1), b = bh / Hc;
    int lane = threadIdx.x;
    int tgrp = lane >> 3, dgrp = lane & 7;
    int t0 = c * 64;
    __shared__ float E[64];
    __shared__ ushort vs[64 * DHc];
    E[lane] = expf(scores[(size_t)bh * Tc + t0 + lane]);
    const ushort* vbase = v + ((size_t)b * Tc + t0) * Dc + h * DHc + dgrp * 8;
    #pragma unroll
    for (int it = 0; it < 8; ++it) {
        int t = it * 8 + tgrp;
        *(ushort8_t*)&vs[t * DHc + dgrp * 8] = *(const ushort8_t*)(vbase + (size_t)t * Dc);
    }
    // inline exclusive prefix over chunks < c
    float acc = 0.f;
    for (int cc = 0; cc < c; ++cc)
        acc += chunkAcc[((size_t)bh * NCc + cc) * DHc + lane];
    float lP = (lane < c) ? chunkL[bh * NCc + lane] : 0.f;
    #pragma unroll
    for (int m = 1; m < 64; m <<= 1) lP += __shfl_xor(lP, m);
    float l = lP;
    __syncthreads();
    #pragma unroll 4
    for (int t = 0; t < 64; t += 2) {
        float e = E[t];
        acc += e * bf2f(vs[t * DHc + lane]);
        l += e;
        int j = (t0 + t) >> 1;
        pooled[((size_t)b * T2c + j) * Dc + h * DHc + lane] = f2bf(acc / l);
        float e2 = E[t + 1];
        acc += e2 * bf2f(vs[(t + 1) * DHc + lane]);
        l += e2;
    }
}

// ---------------------------------------------------------------------------
// K6: LayerNorm (bf16 in -> bf16 out) + fused mag = sigmoid(row . Wm + bm)
// ---------------------------------------------------------------------------
__global__ __launch_bounds__(256) void k_lnmag(const ushort* __restrict__ pooled,
                                               const float* __restrict__ g,
                                               const float* __restrict__ be,
                                               const float* __restrict__ Wm,
                                               const float* __restrict__ bm,
                                               ushort* __restrict__ out,
                                               float* __restrict__ mag) {
    int row = blockIdx.x;
    const ushort* p = pooled + (size_t)row * Dc;
    int tid = threadIdx.x;
    __shared__ float red[256];
    __shared__ float mu_s, rstd_s;
    float x4[4];
    {
        ushort4 u = *(const ushort4*)(p + tid * 4);
        x4[0] = bf2f(u.x); x4[1] = bf2f(u.y); x4[2] = bf2f(u.z); x4[3] = bf2f(u.w);
    }
    red[tid] = x4[0] + x4[1] + x4[2] + x4[3];
    __syncthreads();
    for (int off = 128; off > 0; off >>= 1) {
        if (tid < off) red[tid] += red[tid + off];
        __syncthreads();
    }
    if (tid == 0) mu_s = red[0] * (1.f / Dc);
    __syncthreads();
    float mu = mu_s;
    float vs = 0.f;
    #pragma unroll
    for (int k = 0; k < 4; ++k) { float d = x4[k] - mu; vs += d * d; }
    red[tid] = vs;
    __syncthreads();
    for (int off = 128; off > 0; off >>= 1) {
        if (tid < off) red[tid] += red[tid + off];
        __syncthreads();
    }
    if (tid == 0) rstd_s = rsqrtf(red[0] * (1.f / Dc) + LN_EPS_F);
    __syncthreads();
    float rstd = rstd_s;
    int i = tid * 4;
    float4 gv = *(const float4*)(g + i);
    float4 bv = *(const float4*)(be + i);
    float4 wv = *(const float4*)(Wm + i);
    float n0 = (x4[0] - mu) * rstd * gv.x + bv.x;
    float n1 = (x4[1] - mu) * rstd * gv.y + bv.y;
    float n2 = (x4[2] - mu) * rstd * gv.z + bv.z;
    float n3 = (x4[3] - mu) * rstd * gv.w + bv.w;
    ushort4 o;
    o.x = f2bf(n0); o.y = f2bf(n1); o.z = f2bf(n2); o.w = f2bf(n3);
    *(ushort4*)(out + (size_t)row * Dc + i) = o;
    // fused mag: dot normalized (bf16-rounded, matching GEMM operand) with Wm
    red[tid] = bf2f(o.x) * wv.x + bf2f(o.y) * wv.y + bf2f(o.z) * wv.z + bf2f(o.w) * wv.w;
    __syncthreads();
    for (int off = 128; off > 0; off >>= 1) {
        if (tid < off) red[tid] += red[tid + off];
        __syncthreads();
    }
    if (tid == 0) {
        float z = red[0] + bm[0];
        mag[row] = 1.f / (1.f + expf(-z));
    }
}

// ---------------------------------------------------------------------------
extern "C" void kernel_launch(void* const* d_in, const int* in_sizes, int n_in,
                              void* d_out, int out_size, void* d_ws, size_t ws_size,
                              hipStream_t stream) {
    const float* x     = (const float*)d_in[0];
    const float* query = (const float*)d_in[1];
    const float* Wk    = (const float*)d_in[2];
    const float* Wv    = (const float*)d_in[3];
    const float* Wt    = (const float*)d_in[4];
    const float* bt    = (const float*)d_in[5];
    const float* Wm    = (const float*)d_in[6];
    const float* bm    = (const float*)d_in[7];
    const float* ln_g  = (const float*)d_in[8];
    const float* ln_b  = (const float*)d_in[9];
    float* out = (float*)d_out;

    // workspace layout. NO ALIASING (G16 hazard, hit in R3).
    char* w = (char*)d_ws;
    auto alloc = [&](size_t bytes) { char* p = w; w += (bytes + 255) & ~(size_t)255; return p; };
    ushort* v        = (ushort*)alloc((size_t)Bc * Tc * Dc * 2);      // 16 MB
    ushort* pooled   = (ushort*)alloc((size_t)Bc * T2c * Dc * 2);     // 8 MB
    ushort* xb       = (ushort*)alloc((size_t)Bc * Tc * Dc * 2);      // 16 MB
    ushort* pooledn  = (ushort*)alloc((size_t)Bc * T2c * Dc * 2);     // 8 MB
    ushort* WvXT     = (ushort*)alloc((size_t)NEXT * Dc * 2);         // 2.25 MB
    ushort* WtT      = (ushort*)alloc((size_t)(Dc / 2) * Dc * 2);     // 1 MB
    float*  scores   = (float*) alloc((size_t)Bc * Hc * Tc * 4);      // 512 KB
    float*  chunkL   = (float*) alloc((size_t)Bc * Hc * NCc * 4);
    float*  chunkAcc = (float*) alloc((size_t)Bc * Hc * NCc * DHc * 4);

    // 1) fused prep: xb, WvXT (Wv + qk + pad), WtT
    k_prep<<<PREP_ZERO, 256, 0, stream>>>(x, Wv, Wt, Wk, query, xb, WvXT, WtT);
    // 2) v + scores: direct-global MFMA, one wave per 64x64 tile.
    //    grid y = 17: tiles 0..15 = v cols, 16 = scores cols; pad tile skipped.
    k_gemm_v<<<dim3((Bc * Tc) / 64, 17), 64, 0, stream>>>(xb, WvXT, v, scores);
    // 3) chunk totals
    k_chunk<<<Bc * Hc * NCc, 64, 0, stream>>>(scores, v, chunkL, chunkAcc);
    // 4) emit (inline prefix)
    k_emit<<<Bc * Hc * NCc, 64, 0, stream>>>(scores, v, chunkL, chunkAcc, pooled);
    // 5) LayerNorm + mag
    k_lnmag<<<Bc * T2c, 256, 0, stream>>>(pooled, ln_g, ln_b, Wm, bm, pooledn,
                                          out + (size_t)Bc * T2c * (Dc / 2));
    // 6) theta = pooled_n @ Wt + bt  (4096 x 512 x 1024), direct-global MFMA
    k_gemm_t<<<dim3((Bc * T2c) / 64, (Dc / 2) / 64), 64, 0, stream>>>(
        pooledn, WtT, bt, out, Dc / 2, Dc);
}

// Round 9
// 186.318 us; speedup vs baseline: 1.3174x; 1.3174x over previous
//
#include <hip/hip_runtime.h>
#include <hip/hip_bf16.h>
#include <cstdint>
#include <cstddef>

// Problem constants
constexpr int Bc  = 4;
constexpr int Tc  = 2048;
constexpr int Dc  = 1024;
constexpr int Hc  = 16;
constexpr int DHc = 64;
constexpr int T2c = 1024;
constexpr int NCc = 32;          // chunks per (b,h) row; chunk = 64 timesteps
constexpr int NEXT = 1152;       // extended N for v-GEMM: 1024 v + 16 scores + 112 pad
#define LN_EPS_F 1e-5f

typedef __attribute__((ext_vector_type(8))) short bf16x8;
typedef __attribute__((ext_vector_type(8))) ushort ushort8_t;
typedef __attribute__((ext_vector_type(4))) float f32x4;

__device__ inline ushort f2bf(float f) {
    union { float f; uint32_t u; } v; v.f = f;
    uint32_t r = v.u + 0x7FFFu + ((v.u >> 16) & 1u);   // RNE
    return (ushort)(r >> 16);
}
__device__ inline float bf2f(ushort u) {
    union { uint32_t u; float f; } v; v.u = ((uint32_t)u) << 16;
    return v.f;
}

__device__ inline void async_copy16(const void* g, void* lds) {
    __builtin_amdgcn_global_load_lds(
        (const __attribute__((address_space(1))) void*)g,
        (__attribute__((address_space(3))) void*)lds, 16, 0, 0);
}

// ---------------------------------------------------------------------------
// K0: fused prep (grid-partitioned):
//   [0, 8192)        x fp32 -> xb bf16 (float4 loads)
//   [8192, 9216)     Wv [1024][1024] -> WvXT rows 0..1023   ([n][k] bf16)
//   [9216, 9728)     Wt [1024][512]  -> WtT  [512][1024]
//   [9728, 9792)     qk fold -> WvXT rows 1024..1039  (scale 1/8 folded)
//   [9792, 9848)     zero WvXT rows 1040..1151
// ---------------------------------------------------------------------------
constexpr int PREP_CVT  = 8192;
constexpr int PREP_WV   = PREP_CVT + 1024;
constexpr int PREP_WT   = PREP_WV + 512;
constexpr int PREP_QK   = PREP_WT + 64;
constexpr int PREP_ZERO = PREP_QK + 56;

__global__ __launch_bounds__(256) void k_prep(const float* __restrict__ x,
                                              const float* __restrict__ Wv,
                                              const float* __restrict__ Wt,
                                              const float* __restrict__ Wk,
                                              const float* __restrict__ query,
                                              ushort* __restrict__ xb,
                                              ushort* __restrict__ WvXT,
                                              ushort* __restrict__ WtT) {
    __shared__ float tile[32][33];
    int blk = blockIdx.x;
    int tid = threadIdx.x;
    if (blk < PREP_CVT) {
        int i = (blk * 256 + tid) * 4;
        float4 f = *(const float4*)(x + i);
        ushort4 o;
        o.x = f2bf(f.x); o.y = f2bf(f.y); o.z = f2bf(f.z); o.w = f2bf(f.w);
        *(ushort4*)(xb + i) = o;
    } else if (blk < PREP_WV) {
        int b2 = blk - PREP_CVT;
        int bx = b2 & 31, by = b2 >> 5;              // n-tile, k-tile
        int tx = tid & 31, ty = tid >> 5;
        #pragma unroll
        for (int r = 0; r < 32; r += 8)
            tile[ty + r][tx] = Wv[(size_t)(by * 32 + ty + r) * Dc + bx * 32 + tx];
        __syncthreads();
        #pragma unroll
        for (int r = 0; r < 32; r += 8)
            WvXT[(size_t)(bx * 32 + ty + r) * Dc + by * 32 + tx] = f2bf(tile[tx][ty + r]);
    } else if (blk < PREP_WT) {
        int b2 = blk - PREP_WV;
        int bx = b2 & 15, by = b2 >> 4;              // n-tile (512), k-tile (1024)
        int tx = tid & 31, ty = tid >> 5;
        #pragma unroll
        for (int r = 0; r < 32; r += 8)
            tile[ty + r][tx] = Wt[(size_t)(by * 32 + ty + r) * (Dc / 2) + bx * 32 + tx];
        __syncthreads();
        #pragma unroll
        for (int r = 0; r < 32; r += 8)
            WtT[(size_t)(bx * 32 + ty + r) * Dc + by * 32 + tx] = f2bf(tile[tx][ty + r]);
    } else if (blk < PREP_QK) {
        int idx = (blk - PREP_WT) * 256 + tid;       // 0..16383
        int h = idx >> 10, i = idx & (Dc - 1);
        const float* wrow = Wk + (size_t)i * Dc + h * DHc;
        const float* qh   = query + h * DHc;
        float s = 0.f;
        #pragma unroll 8
        for (int d = 0; d < DHc; ++d) s += wrow[d] * qh[d];
        WvXT[(size_t)(Dc + h) * Dc + i] = f2bf(s * 0.125f);
    } else {
        int idx = (blk - PREP_QK) * 256 + tid;       // 0..14335 -> 8 ushorts each
        uint4 z = {0, 0, 0, 0};
        *(uint4*)(WvXT + (size_t)1040 * Dc + idx * 8) = z;
    }
}

// ---------------------------------------------------------------------------
// K4a: v-GEMM + scores.  BM=128, BN=64, BK=32, 4 waves (2x2, wave tile 64x32).
//   LDS-staged m97 structure; grid (M/128 row-fastest for XCD, 17 col tiles).
//   1088 blocks (~4.25/CU) vs R7's 576 — more resident waves to overlap the
//   per-iter vmcnt drain. cols<1024 -> v bf16; 1024..1039 -> scores fp32.
// ---------------------------------------------------------------------------
__global__ __launch_bounds__(256) void k_gemm_v(const ushort* __restrict__ A,
                                                const ushort* __restrict__ Bt,
                                                ushort* __restrict__ v,
                                                float* __restrict__ scores) {
    constexpr int K = Dc;
    __shared__ ushort As[128 * 32];
    __shared__ ushort Bs[64 * 32];
    int tid = threadIdx.x;
    int wid = tid >> 6, lane = tid & 63;
    int tile_m = blockIdx.x * 128, tile_n = blockIdx.y * 64;   // row fastest (XCD)
    int wm = wid >> 1, wn = wid & 1;                 // wave tile 64x32

    f32x4 acc[4][2] = {};

    int lrow = lane >> 2;                            // 0..15
    int lchunk = lane & 3;                           // 16B chunk in 64B row
    int quad = lane >> 4, l15 = lane & 15;

    for (int k0 = 0; k0 < K; k0 += 32) {
        // A: 8 rowgrps of 16 rows; wave stages 2
        #pragma unroll
        for (int r = 0; r < 2; ++r) {
            int rowgrp = wid * 2 + r;
            int row = rowgrp * 16 + lrow;
            async_copy16(A + (size_t)(tile_m + row) * K + k0 + lchunk * 8,
                         &As[rowgrp * 16 * 32]);
        }
        // B: 4 rowgrps; wave stages 1
        {
            int row = wid * 16 + lrow;
            async_copy16(Bt + (size_t)(tile_n + row) * K + k0 + lchunk * 8,
                         &Bs[wid * 16 * 32]);
        }
        __syncthreads();

        bf16x8 a_frag[4], b_frag[2];
        #pragma unroll
        for (int i = 0; i < 4; ++i)
            a_frag[i] = *(const bf16x8*)&As[(wm * 64 + i * 16 + l15) * 32 + quad * 8];
        #pragma unroll
        for (int j = 0; j < 2; ++j)
            b_frag[j] = *(const bf16x8*)&Bs[(wn * 32 + j * 16 + l15) * 32 + quad * 8];
        #pragma unroll
        for (int i = 0; i < 4; ++i)
            #pragma unroll
            for (int j = 0; j < 2; ++j)
                acc[i][j] = __builtin_amdgcn_mfma_f32_16x16x32_bf16(
                    a_frag[i], b_frag[j], acc[i][j], 0, 0, 0);
        __syncthreads();
    }

    // epilogue: C/D mapping col=lane&15, row=quad*4+reg
    #pragma unroll
    for (int j = 0; j < 2; ++j) {
        int col = tile_n + wn * 32 + j * 16 + l15;
        #pragma unroll
        for (int i = 0; i < 4; ++i) {
            #pragma unroll
            for (int r = 0; r < 4; ++r) {
                int row = tile_m + wm * 64 + i * 16 + quad * 4 + r;
                float val = acc[i][j][r];
                if (col < Dc) {
                    v[(size_t)row * Dc + col] = f2bf(val);
                } else if (col < Dc + Hc) {
                    int h = col - Dc;
                    int b2 = row >> 11, t = row & (Tc - 1);
                    scores[((size_t)b2 * Hc + h) * Tc + t] = val;
                }
            }
        }
    }
}

// ---------------------------------------------------------------------------
// K4b: theta GEMM. BM=64, BN=64, BK=32, 4 waves (2x2, wave tile 32x32).
//   grid (M/64=64 row-fastest, N/64=8) = 512 blocks (~2/CU; R7 had 128).
// ---------------------------------------------------------------------------
__global__ __launch_bounds__(256) void k_gemm_t(const ushort* __restrict__ A,
                                                const ushort* __restrict__ Bt,
                                                const float* __restrict__ bias,
                                                float* __restrict__ C,
                                                int N, int K) {
    __shared__ ushort As[64 * 32];
    __shared__ ushort Bs[64 * 32];
    int tid = threadIdx.x;
    int wid = tid >> 6, lane = tid & 63;
    int tile_m = blockIdx.x * 64, tile_n = blockIdx.y * 64;   // row fastest (XCD)
    int wm = wid >> 1, wn = wid & 1;                 // wave tile 32x32

    f32x4 acc[2][2] = {};

    int lrow = lane >> 2;
    int lchunk = lane & 3;
    int quad = lane >> 4, l15 = lane & 15;

    for (int k0 = 0; k0 < K; k0 += 32) {
        {
            int row = wid * 16 + lrow;
            async_copy16(A + (size_t)(tile_m + row) * K + k0 + lchunk * 8,
                         &As[wid * 16 * 32]);
            async_copy16(Bt + (size_t)(tile_n + row) * K + k0 + lchunk * 8,
                         &Bs[wid * 16 * 32]);
        }
        __syncthreads();

        bf16x8 a_frag[2], b_frag[2];
        #pragma unroll
        for (int i = 0; i < 2; ++i)
            a_frag[i] = *(const bf16x8*)&As[(wm * 32 + i * 16 + l15) * 32 + quad * 8];
        #pragma unroll
        for (int j = 0; j < 2; ++j)
            b_frag[j] = *(const bf16x8*)&Bs[(wn * 32 + j * 16 + l15) * 32 + quad * 8];
        #pragma unroll
        for (int i = 0; i < 2; ++i)
            #pragma unroll
            for (int j = 0; j < 2; ++j)
                acc[i][j] = __builtin_amdgcn_mfma_f32_16x16x32_bf16(
                    a_frag[i], b_frag[j], acc[i][j], 0, 0, 0);
        __syncthreads();
    }

    #pragma unroll
    for (int j = 0; j < 2; ++j) {
        int col = tile_n + wn * 32 + j * 16 + l15;
        float bv = bias[col];
        #pragma unroll
        for (int i = 0; i < 2; ++i) {
            #pragma unroll
            for (int r = 0; r < 4; ++r) {
                int row = tile_m + wm * 32 + i * 16 + quad * 4 + r;
                C[(size_t)row * N + col] = acc[i][j][r] + bv;
            }
        }
    }
}

// ---------------------------------------------------------------------------
// K5a: per-chunk totals of E_t and E_t * v[t,h,:]  (shift-free softmax)
// ---------------------------------------------------------------------------
__global__ __launch_bounds__(64) void k_chunk(const float* __restrict__ scores,
                                              const ushort* __restrict__ v,
                                              float* __restrict__ chunkL,
                                              float* __restrict__ chunkAcc) {
    int idx = blockIdx.x;
    int c = idx & (NCc - 1);
    int bh = idx / NCc;
    int h = bh & (Hc - 1), b = bh / Hc;
    int lane = threadIdx.x;
    int tgrp = lane >> 3;
    int dgrp = lane & 7;
    int t0 = c * 64;
    const float* srow = scores + (size_t)bh * Tc + t0;
    const ushort* vbase = v + ((size_t)b * Tc + t0) * Dc + h * DHc + dgrp * 8;
    float acc[8] = {};
    float lsum = 0.f;
    #pragma unroll
    for (int it = 0; it < 8; ++it) {
        int t = it * 8 + tgrp;
        float e = expf(srow[t]);
        ushort8_t vv = *(const ushort8_t*)(vbase + (size_t)t * Dc);
        #pragma unroll
        for (int k = 0; k < 8; ++k) acc[k] += e * bf2f(vv[k]);
        lsum += e;
    }
    #pragma unroll
    for (int m = 8; m < 64; m <<= 1) {
        #pragma unroll
        for (int k = 0; k < 8; ++k) acc[k] += __shfl_xor(acc[k], m);
        lsum += __shfl_xor(lsum, m);
    }
    if (tgrp == 0) {
        float4 lo = {acc[0], acc[1], acc[2], acc[3]};
        float4 hi = {acc[4], acc[5], acc[6], acc[7]};
        *(float4*)&chunkAcc[(size_t)idx * DHc + dgrp * 8]     = lo;
        *(float4*)&chunkAcc[(size_t)idx * DHc + dgrp * 8 + 4] = hi;
        if (dgrp == 0) chunkL[idx] = lsum;
    }
}

// ---------------------------------------------------------------------------
// K5c: within-chunk scan + emit (prefix over prior chunks computed inline)
// ---------------------------------------------------------------------------
__global__ __launch_bounds__(64) void k_emit(const float* __restrict__ scores,
                                             const ushort* __restrict__ v,
                                             const float* __restrict__ chunkL,
                                             const float* __restrict__ chunkAcc,
                                             ushort* __restrict__ pooled) {
    int idx = blockIdx.x;
    int c = idx & (NCc - 1);
    int bh = idx / NCc;
    int h = bh & (Hc - 1), b = bh / Hc;
    int lane = threadIdx.x;
    int tgrp = lane >> 3, dgrp = lane & 7;
    int t0 = c * 64;
    __shared__ float E[64];
    __shared__ ushort vs[64 * DHc];
    E[lane] = expf(scores[(size_t)bh * Tc + t0 + lane]);
    const ushort* vbase = v + ((size_t)b * Tc + t0) * Dc + h * DHc + dgrp * 8;
    #pragma unroll
    for (int it = 0; it < 8; ++it) {
        int t = it * 8 + tgrp;
        *(ushort8_t*)&vs[t * DHc + dgrp * 8] = *(const ushort8_t*)(vbase + (size_t)t * Dc);
    }
    // inline exclusive prefix over chunks < c
    float acc = 0.f;
    for (int cc = 0; cc < c; ++cc)
        acc += chunkAcc[((size_t)bh * NCc + cc) * DHc + lane];
    float lP = (lane < c) ? chunkL[bh * NCc + lane] : 0.f;
    #pragma unroll
    for (int m = 1; m < 64; m <<= 1) lP += __shfl_xor(lP, m);
    float l = lP;
    __syncthreads();
    #pragma unroll 4
    for (int t = 0; t < 64; t += 2) {
        float e = E[t];
        acc += e * bf2f(vs[t * DHc + lane]);
        l += e;
        int j = (t0 + t) >> 1;
        pooled[((size_t)b * T2c + j) * Dc + h * DHc + lane] = f2bf(acc / l);
        float e2 = E[t + 1];
        acc += e2 * bf2f(vs[(t + 1) * DHc + lane]);
        l += e2;
    }
}

// ---------------------------------------------------------------------------
// K6: LayerNorm (bf16 in -> bf16 out) + fused mag = sigmoid(row . Wm + bm)
// ---------------------------------------------------------------------------
__global__ __launch_bounds__(256) void k_lnmag(const ushort* __restrict__ pooled,
                                               const float* __restrict__ g,
                                               const float* __restrict__ be,
                                               const float* __restrict__ Wm,
                                               const float* __restrict__ bm,
                                               ushort* __restrict__ out,
                                               float* __restrict__ mag) {
    int row = blockIdx.x;
    const ushort* p = pooled + (size_t)row * Dc;
    int tid = threadIdx.x;
    __shared__ float red[256];
    __shared__ float mu_s, rstd_s;
    float x4[4];
    {
        ushort4 u = *(const ushort4*)(p + tid * 4);
        x4[0] = bf2f(u.x); x4[1] = bf2f(u.y); x4[2] = bf2f(u.z); x4[3] = bf2f(u.w);
    }
    red[tid] = x4[0] + x4[1] + x4[2] + x4[3];
    __syncthreads();
    for (int off = 128; off > 0; off >>= 1) {
        if (tid < off) red[tid] += red[tid + off];
        __syncthreads();
    }
    if (tid == 0) mu_s = red[0] * (1.f / Dc);
    __syncthreads();
    float mu = mu_s;
    float vs = 0.f;
    #pragma unroll
    for (int k = 0; k < 4; ++k) { float d = x4[k] - mu; vs += d * d; }
    red[tid] = vs;
    __syncthreads();
    for (int off = 128; off > 0; off >>= 1) {
        if (tid < off) red[tid] += red[tid + off];
        __syncthreads();
    }
    if (tid == 0) rstd_s = rsqrtf(red[0] * (1.f / Dc) + LN_EPS_F);
    __syncthreads();
    float rstd = rstd_s;
    int i = tid * 4;
    float4 gv = *(const float4*)(g + i);
    float4 bv = *(const float4*)(be + i);
    float4 wv = *(const float4*)(Wm + i);
    float n0 = (x4[0] - mu) * rstd * gv.x + bv.x;
    float n1 = (x4[1] - mu) * rstd * gv.y + bv.y;
    float n2 = (x4[2] - mu) * rstd * gv.z + bv.z;
    float n3 = (x4[3] - mu) * rstd * gv.w + bv.w;
    ushort4 o;
    o.x = f2bf(n0); o.y = f2bf(n1); o.z = f2bf(n2); o.w = f2bf(n3);
    *(ushort4*)(out + (size_t)row * Dc + i) = o;
    // fused mag: dot normalized (bf16-rounded, matching GEMM operand) with Wm
    red[tid] = bf2f(o.x) * wv.x + bf2f(o.y) * wv.y + bf2f(o.z) * wv.z + bf2f(o.w) * wv.w;
    __syncthreads();
    for (int off = 128; off > 0; off >>= 1) {
        if (tid < off) red[tid] += red[tid + off];
        __syncthreads();
    }
    if (tid == 0) {
        float z = red[0] + bm[0];
        mag[row] = 1.f / (1.f + expf(-z));
    }
}

// ---------------------------------------------------------------------------
extern "C" void kernel_launch(void* const* d_in, const int* in_sizes, int n_in,
                              void* d_out, int out_size, void* d_ws, size_t ws_size,
                              hipStream_t stream) {
    const float* x     = (const float*)d_in[0];
    const float* query = (const float*)d_in[1];
    const float* Wk    = (const float*)d_in[2];
    const float* Wv    = (const float*)d_in[3];
    const float* Wt    = (const float*)d_in[4];
    const float* bt    = (const float*)d_in[5];
    const float* Wm    = (const float*)d_in[6];
    const float* bm    = (const float*)d_in[7];
    const float* ln_g  = (const float*)d_in[8];
    const float* ln_b  = (const float*)d_in[9];
    float* out = (float*)d_out;

    // workspace layout. NO ALIASING (G16 hazard, hit in R3).
    char* w = (char*)d_ws;
    auto alloc = [&](size_t bytes) { char* p = w; w += (bytes + 255) & ~(size_t)255; return p; };
    ushort* v        = (ushort*)alloc((size_t)Bc * Tc * Dc * 2);      // 16 MB
    ushort* pooled   = (ushort*)alloc((size_t)Bc * T2c * Dc * 2);     // 8 MB
    ushort* xb       = (ushort*)alloc((size_t)Bc * Tc * Dc * 2);      // 16 MB
    ushort* pooledn  = (ushort*)alloc((size_t)Bc * T2c * Dc * 2);     // 8 MB
    ushort* WvXT     = (ushort*)alloc((size_t)NEXT * Dc * 2);         // 2.25 MB
    ushort* WtT      = (ushort*)alloc((size_t)(Dc / 2) * Dc * 2);     // 1 MB
    float*  scores   = (float*) alloc((size_t)Bc * Hc * Tc * 4);      // 512 KB
    float*  chunkL   = (float*) alloc((size_t)Bc * Hc * NCc * 4);
    float*  chunkAcc = (float*) alloc((size_t)Bc * Hc * NCc * DHc * 4);

    // 1) fused prep: xb, WvXT (Wv + qk + pad), WtT
    k_prep<<<PREP_ZERO, 256, 0, stream>>>(x, Wv, Wt, Wk, query, xb, WvXT, WtT);
    // 2) v + scores: BM=128 BN=64 LDS MFMA; grid (64 row-tiles fastest, 17 col
    //    tiles: 0..15 v, 16 = scores; pad tile 17 not launched) = 1088 blocks.
    k_gemm_v<<<dim3((Bc * Tc) / 128, 17), 256, 0, stream>>>(xb, WvXT, v, scores);
    // 3) chunk totals
    k_chunk<<<Bc * Hc * NCc, 64, 0, stream>>>(scores, v, chunkL, chunkAcc);
    // 4) emit (inline prefix)
    k_emit<<<Bc * Hc * NCc, 64, 0, stream>>>(scores, v, chunkL, chunkAcc, pooled);
    // 5) LayerNorm + mag
    k_lnmag<<<Bc * T2c, 256, 0, stream>>>(pooled, ln_g, ln_b, Wm, bm, pooledn,
                                          out + (size_t)Bc * T2c * (Dc / 2));
    // 6) theta = pooled_n @ Wt + bt  (4096 x 512 x 1024), BM=64 BN=64, 512 blocks
    k_gemm_t<<<dim3((Bc * T2c) / 64, (Dc / 2) / 64), 256, 0, stream>>>(
        pooledn, WtT, bt, out, Dc / 2, Dc);
}

// Round 10
// 177.582 us; speedup vs baseline: 1.3822x; 1.0492x over previous
//
#include <hip/hip_runtime.h>
#include <hip/hip_bf16.h>
#include <cstdint>
#include <cstddef>

// Problem constants
constexpr int Bc  = 4;
constexpr int Tc  = 2048;
constexpr int Dc  = 1024;
constexpr int Hc  = 16;
constexpr int DHc = 64;
constexpr int T2c = 1024;
constexpr int NCc = 32;          // chunks per (b,h) row; chunk = 64 timesteps
constexpr int NEXT = 1152;       // extended N for v-GEMM: 1024 v + 16 scores + 112 pad
#define LN_EPS_F 1e-5f

typedef __attribute__((ext_vector_type(8))) short bf16x8;
typedef __attribute__((ext_vector_type(8))) ushort ushort8_t;
typedef __attribute__((ext_vector_type(4))) float f32x4;

__device__ inline ushort f2bf(float f) {
    union { float f; uint32_t u; } v; v.f = f;
    uint32_t r = v.u + 0x7FFFu + ((v.u >> 16) & 1u);   // RNE
    return (ushort)(r >> 16);
}
__device__ inline float bf2f(ushort u) {
    union { uint32_t u; float f; } v; v.u = ((uint32_t)u) << 16;
    return v.f;
}

__device__ inline void async_copy16(const void* g, void* lds) {
    __builtin_amdgcn_global_load_lds(
        (const __attribute__((address_space(1))) void*)g,
        (__attribute__((address_space(3))) void*)lds, 16, 0, 0);
}

// ---------------------------------------------------------------------------
// K0: fused prep (grid-partitioned):
//   [0, 8192)        x fp32 -> xb bf16 (float4 loads)
//   [8192, 9216)     Wv [1024][1024] -> WvXT rows 0..1023   ([n][k] bf16)
//   [9216, 9728)     Wt [1024][512]  -> WtT  [512][1024]
//   [9728, 9792)     qk fold -> WvXT rows 1024..1039  (scale 1/8 folded)
//   [9792, 9848)     zero WvXT rows 1040..1151
// ---------------------------------------------------------------------------
constexpr int PREP_CVT  = 8192;
constexpr int PREP_WV   = PREP_CVT + 1024;
constexpr int PREP_WT   = PREP_WV + 512;
constexpr int PREP_QK   = PREP_WT + 64;
constexpr int PREP_ZERO = PREP_QK + 56;

__global__ __launch_bounds__(256) void k_prep(const float* __restrict__ x,
                                              const float* __restrict__ Wv,
                                              const float* __restrict__ Wt,
                                              const float* __restrict__ Wk,
                                              const float* __restrict__ query,
                                              ushort* __restrict__ xb,
                                              ushort* __restrict__ WvXT,
                                              ushort* __restrict__ WtT) {
    __shared__ float tile[32][33];
    int blk = blockIdx.x;
    int tid = threadIdx.x;
    if (blk < PREP_CVT) {
        int i = (blk * 256 + tid) * 4;
        float4 f = *(const float4*)(x + i);
        ushort4 o;
        o.x = f2bf(f.x); o.y = f2bf(f.y); o.z = f2bf(f.z); o.w = f2bf(f.w);
        *(ushort4*)(xb + i) = o;
    } else if (blk < PREP_WV) {
        int b2 = blk - PREP_CVT;
        int bx = b2 & 31, by = b2 >> 5;              // n-tile, k-tile
        int tx = tid & 31, ty = tid >> 5;
        #pragma unroll
        for (int r = 0; r < 32; r += 8)
            tile[ty + r][tx] = Wv[(size_t)(by * 32 + ty + r) * Dc + bx * 32 + tx];
        __syncthreads();
        #pragma unroll
        for (int r = 0; r < 32; r += 8)
            WvXT[(size_t)(bx * 32 + ty + r) * Dc + by * 32 + tx] = f2bf(tile[tx][ty + r]);
    } else if (blk < PREP_WT) {
        int b2 = blk - PREP_WV;
        int bx = b2 & 15, by = b2 >> 4;              // n-tile (512), k-tile (1024)
        int tx = tid & 31, ty = tid >> 5;
        #pragma unroll
        for (int r = 0; r < 32; r += 8)
            tile[ty + r][tx] = Wt[(size_t)(by * 32 + ty + r) * (Dc / 2) + bx * 32 + tx];
        __syncthreads();
        #pragma unroll
        for (int r = 0; r < 32; r += 8)
            WtT[(size_t)(bx * 32 + ty + r) * Dc + by * 32 + tx] = f2bf(tile[tx][ty + r]);
    } else if (blk < PREP_QK) {
        int idx = (blk - PREP_WT) * 256 + tid;       // 0..16383
        int h = idx >> 10, i = idx & (Dc - 1);
        const float* wrow = Wk + (size_t)i * Dc + h * DHc;
        const float* qh   = query + h * DHc;
        float s = 0.f;
        #pragma unroll 8
        for (int d = 0; d < DHc; ++d) s += wrow[d] * qh[d];
        WvXT[(size_t)(Dc + h) * Dc + i] = f2bf(s * 0.125f);
    } else {
        int idx = (blk - PREP_QK) * 256 + tid;       // 0..14335 -> 8 ushorts each
        uint4 z = {0, 0, 0, 0};
        *(uint4*)(WvXT + (size_t)1040 * Dc + idx * 8) = z;
    }
}

// ---------------------------------------------------------------------------
// K4a: v-GEMM + scores.  BM=128, BN=64, BK=64, 4 waves (2x2, wave tile 64x32).
//   16 K-iterations (half the barriers of BK=32), XOR-swizzled LDS:
//   LDS[row][c] holds global 16B-chunk c^(row&7) -> frag ds_read_b128 bank
//   footprint spreads over all 8 groups (was 8-way conflict, 3.3M counts).
//   Staging stays fully coalesced (chunks permuted within each 128B row).
//   grid (M/128 row-fastest for XCD, 17 col tiles).
// ---------------------------------------------------------------------------
__global__ __launch_bounds__(256) void k_gemm_v(const ushort* __restrict__ A,
                                                const ushort* __restrict__ Bt,
                                                ushort* __restrict__ v,
                                                float* __restrict__ scores) {
    constexpr int K = Dc;
    __shared__ ushort As[128 * 64];                  // 16 KB
    __shared__ ushort Bs[64 * 64];                   // 8 KB
    int tid = threadIdx.x;
    int wid = tid >> 6, lane = tid & 63;
    int tile_m = blockIdx.x * 128, tile_n = blockIdx.y * 64;   // row fastest (XCD)
    int wm = wid >> 1, wn = wid & 1;                 // wave tile 64x32

    f32x4 acc[4][2] = {};

    int lrow = lane >> 3;                            // 0..7 (row within 8-row grp)
    int lchunk = lane & 7;                           // 0..7 (16B chunk of 128B row)
    int schunk = lchunk ^ lrow;                      // swizzled source chunk
    int quad = lane >> 4, l15 = lane & 15;
    int sw = l15 & 7;                                // row&7 for frag reads

    for (int k0 = 0; k0 < K; k0 += 64) {
        // A: 16 rowgrps of 8 rows; wave stages 4 (1 KB each)
        #pragma unroll
        for (int r = 0; r < 4; ++r) {
            int rowgrp = wid * 4 + r;                // 0..15
            int row = rowgrp * 8 + lrow;
            async_copy16(A + (size_t)(tile_m + row) * K + k0 + schunk * 8,
                         &As[rowgrp * 8 * 64]);
        }
        // B: 8 rowgrps; wave stages 2
        #pragma unroll
        for (int r = 0; r < 2; ++r) {
            int rowgrp = wid * 2 + r;                // 0..7
            int row = rowgrp * 8 + lrow;
            async_copy16(Bt + (size_t)(tile_n + row) * K + k0 + schunk * 8,
                         &Bs[rowgrp * 8 * 64]);
        }
        __syncthreads();

        bf16x8 a_frag[4][2], b_frag[2][2];
        #pragma unroll
        for (int s = 0; s < 2; ++s) {
            int gc = s * 4 + quad;                   // global chunk wanted
            #pragma unroll
            for (int i = 0; i < 4; ++i)
                a_frag[i][s] = *(const bf16x8*)&As[(wm * 64 + i * 16 + l15) * 64 + ((gc ^ sw) * 8)];
            #pragma unroll
            for (int j = 0; j < 2; ++j)
                b_frag[j][s] = *(const bf16x8*)&Bs[(wn * 32 + j * 16 + l15) * 64 + ((gc ^ sw) * 8)];
        }
        #pragma unroll
        for (int s = 0; s < 2; ++s)
            #pragma unroll
            for (int i = 0; i < 4; ++i)
                #pragma unroll
                for (int j = 0; j < 2; ++j)
                    acc[i][j] = __builtin_amdgcn_mfma_f32_16x16x32_bf16(
                        a_frag[i][s], b_frag[j][s], acc[i][j], 0, 0, 0);
        __syncthreads();
    }

    // epilogue: C/D mapping col=lane&15, row=quad*4+reg
    #pragma unroll
    for (int j = 0; j < 2; ++j) {
        int col = tile_n + wn * 32 + j * 16 + l15;
        #pragma unroll
        for (int i = 0; i < 4; ++i) {
            #pragma unroll
            for (int r = 0; r < 4; ++r) {
                int row = tile_m + wm * 64 + i * 16 + quad * 4 + r;
                float val = acc[i][j][r];
                if (col < Dc) {
                    v[(size_t)row * Dc + col] = f2bf(val);
                } else if (col < Dc + Hc) {
                    int h = col - Dc;
                    int b2 = row >> 11, t = row & (Tc - 1);
                    scores[((size_t)b2 * Hc + h) * Tc + t] = val;
                }
            }
        }
    }
}

// ---------------------------------------------------------------------------
// K4b: theta GEMM. BM=64, BN=64, BK=64, 4 waves (2x2, wave tile 32x32).
//   Same swizzle. grid (M/64=64 row-fastest, N/64=8) = 512 blocks.
// ---------------------------------------------------------------------------
__global__ __launch_bounds__(256) void k_gemm_t(const ushort* __restrict__ A,
                                                const ushort* __restrict__ Bt,
                                                const float* __restrict__ bias,
                                                float* __restrict__ C,
                                                int N, int K) {
    __shared__ ushort As[64 * 64];                   // 8 KB
    __shared__ ushort Bs[64 * 64];                   // 8 KB
    int tid = threadIdx.x;
    int wid = tid >> 6, lane = tid & 63;
    int tile_m = blockIdx.x * 64, tile_n = blockIdx.y * 64;   // row fastest (XCD)
    int wm = wid >> 1, wn = wid & 1;                 // wave tile 32x32

    f32x4 acc[2][2] = {};

    int lrow = lane >> 3;
    int lchunk = lane & 7;
    int schunk = lchunk ^ lrow;
    int quad = lane >> 4, l15 = lane & 15;
    int sw = l15 & 7;

    for (int k0 = 0; k0 < K; k0 += 64) {
        #pragma unroll
        for (int r = 0; r < 2; ++r) {
            int rowgrp = wid * 2 + r;                // 0..7
            int row = rowgrp * 8 + lrow;
            async_copy16(A + (size_t)(tile_m + row) * K + k0 + schunk * 8,
                         &As[rowgrp * 8 * 64]);
            async_copy16(Bt + (size_t)(tile_n + row) * K + k0 + schunk * 8,
                         &Bs[rowgrp * 8 * 64]);
        }
        __syncthreads();

        bf16x8 a_frag[2][2], b_frag[2][2];
        #pragma unroll
        for (int s = 0; s < 2; ++s) {
            int gc = s * 4 + quad;
            #pragma unroll
            for (int i = 0; i < 2; ++i)
                a_frag[i][s] = *(const bf16x8*)&As[(wm * 32 + i * 16 + l15) * 64 + ((gc ^ sw) * 8)];
            #pragma unroll
            for (int j = 0; j < 2; ++j)
                b_frag[j][s] = *(const bf16x8*)&Bs[(wn * 32 + j * 16 + l15) * 64 + ((gc ^ sw) * 8)];
        }
        #pragma unroll
        for (int s = 0; s < 2; ++s)
            #pragma unroll
            for (int i = 0; i < 2; ++i)
                #pragma unroll
                for (int j = 0; j < 2; ++j)
                    acc[i][j] = __builtin_amdgcn_mfma_f32_16x16x32_bf16(
                        a_frag[i][s], b_frag[j][s], acc[i][j], 0, 0, 0);
        __syncthreads();
    }

    #pragma unroll
    for (int j = 0; j < 2; ++j) {
        int col = tile_n + wn * 32 + j * 16 + l15;
        float bv = bias[col];
        #pragma unroll
        for (int i = 0; i < 2; ++i) {
            #pragma unroll
            for (int r = 0; r < 4; ++r) {
                int row = tile_m + wm * 32 + i * 16 + quad * 4 + r;
                C[(size_t)row * N + col] = acc[i][j][r] + bv;
            }
        }
    }
}

// ---------------------------------------------------------------------------
// K5a: per-chunk totals of E_t and E_t * v[t,h,:]  (shift-free softmax)
// ---------------------------------------------------------------------------
__global__ __launch_bounds__(64) void k_chunk(const float* __restrict__ scores,
                                              const ushort* __restrict__ v,
                                              float* __restrict__ chunkL,
                                              float* __restrict__ chunkAcc) {
    int idx = blockIdx.x;
    int c = idx & (NCc - 1);
    int bh = idx / NCc;
    int h = bh & (Hc - 1), b = bh / Hc;
    int lane = threadIdx.x;
    int tgrp = lane >> 3;
    int dgrp = lane & 7;
    int t0 = c * 64;
    const float* srow = scores + (size_t)bh * Tc + t0;
    const ushort* vbase = v + ((size_t)b * Tc + t0) * Dc + h * DHc + dgrp * 8;
    float acc[8] = {};
    float lsum = 0.f;
    #pragma unroll
    for (int it = 0; it < 8; ++it) {
        int t = it * 8 + tgrp;
        float e = expf(srow[t]);
        ushort8_t vv = *(const ushort8_t*)(vbase + (size_t)t * Dc);
        #pragma unroll
        for (int k = 0; k < 8; ++k) acc[k] += e * bf2f(vv[k]);
        lsum += e;
    }
    #pragma unroll
    for (int m = 8; m < 64; m <<= 1) {
        #pragma unroll
        for (int k = 0; k < 8; ++k) acc[k] += __shfl_xor(acc[k], m);
        lsum += __shfl_xor(lsum, m);
    }
    if (tgrp == 0) {
        float4 lo = {acc[0], acc[1], acc[2], acc[3]};
        float4 hi = {acc[4], acc[5], acc[6], acc[7]};
        *(float4*)&chunkAcc[(size_t)idx * DHc + dgrp * 8]     = lo;
        *(float4*)&chunkAcc[(size_t)idx * DHc + dgrp * 8 + 4] = hi;
        if (dgrp == 0) chunkL[idx] = lsum;
    }
}

// ---------------------------------------------------------------------------
// K5c: within-chunk scan + emit (prefix over prior chunks computed inline)
// ---------------------------------------------------------------------------
__global__ __launch_bounds__(64) void k_emit(const float* __restrict__ scores,
                                             const ushort* __restrict__ v,
                                             const float* __restrict__ chunkL,
                                             const float* __restrict__ chunkAcc,
                                             ushort* __restrict__ pooled) {
    int idx = blockIdx.x;
    int c = idx & (NCc - 1);
    int bh = idx / NCc;
    int h = bh & (Hc - 1), b = bh / Hc;
    int lane = threadIdx.x;
    int tgrp = lane >> 3, dgrp = lane & 7;
    int t0 = c * 64;
    __shared__ float E[64];
    __shared__ ushort vs[64 * DHc];
    E[lane] = expf(scores[(size_t)bh * Tc + t0 + lane]);
    const ushort* vbase = v + ((size_t)b * Tc + t0) * Dc + h * DHc + dgrp * 8;
    #pragma unroll
    for (int it = 0; it < 8; ++it) {
        int t = it * 8 + tgrp;
        *(ushort8_t*)&vs[t * DHc + dgrp * 8] = *(const ushort8_t*)(vbase + (size_t)t * Dc);
    }
    // inline exclusive prefix over chunks < c
    float acc = 0.f;
    for (int cc = 0; cc < c; ++cc)
        acc += chunkAcc[((size_t)bh * NCc + cc) * DHc + lane];
    float lP = (lane < c) ? chunkL[bh * NCc + lane] : 0.f;
    #pragma unroll
    for (int m = 1; m < 64; m <<= 1) lP += __shfl_xor(lP, m);
    float l = lP;
    __syncthreads();
    #pragma unroll 4
    for (int t = 0; t < 64; t += 2) {
        float e = E[t];
        acc += e * bf2f(vs[t * DHc + lane]);
        l += e;
        int j = (t0 + t) >> 1;
        pooled[((size_t)b * T2c + j) * Dc + h * DHc + lane] = f2bf(acc / l);
        float e2 = E[t + 1];
        acc += e2 * bf2f(vs[(t + 1) * DHc + lane]);
        l += e2;
    }
}

// ---------------------------------------------------------------------------
// K6: LayerNorm (bf16 in -> bf16 out) + fused mag = sigmoid(row . Wm + bm)
// ---------------------------------------------------------------------------
__global__ __launch_bounds__(256) void k_lnmag(const ushort* __restrict__ pooled,
                                               const float* __restrict__ g,
                                               const float* __restrict__ be,
                                               const float* __restrict__ Wm,
                                               const float* __restrict__ bm,
                                               ushort* __restrict__ out,
                                               float* __restrict__ mag) {
    int row = blockIdx.x;
    const ushort* p = pooled + (size_t)row * Dc;
    int tid = threadIdx.x;
    __shared__ float red[256];
    __shared__ float mu_s, rstd_s;
    float x4[4];
    {
        ushort4 u = *(const ushort4*)(p + tid * 4);
        x4[0] = bf2f(u.x); x4[1] = bf2f(u.y); x4[2] = bf2f(u.z); x4[3] = bf2f(u.w);
    }
    red[tid] = x4[0] + x4[1] + x4[2] + x4[3];
    __syncthreads();
    for (int off = 128; off > 0; off >>= 1) {
        if (tid < off) red[tid] += red[tid + off];
        __syncthreads();
    }
    if (tid == 0) mu_s = red[0] * (1.f / Dc);
    __syncthreads();
    float mu = mu_s;
    float vs = 0.f;
    #pragma unroll
    for (int k = 0; k < 4; ++k) { float d = x4[k] - mu; vs += d * d; }
    red[tid] = vs;
    __syncthreads();
    for (int off = 128; off > 0; off >>= 1) {
        if (tid < off) red[tid] += red[tid + off];
        __syncthreads();
    }
    if (tid == 0) rstd_s = rsqrtf(red[0] * (1.f / Dc) + LN_EPS_F);
    __syncthreads();
    float rstd = rstd_s;
    int i = tid * 4;
    float4 gv = *(const float4*)(g + i);
    float4 bv = *(const float4*)(be + i);
    float4 wv = *(const float4*)(Wm + i);
    float n0 = (x4[0] - mu) * rstd * gv.x + bv.x;
    float n1 = (x4[1] - mu) * rstd * gv.y + bv.y;
    float n2 = (x4[2] - mu) * rstd * gv.z + bv.z;
    float n3 = (x4[3] - mu) * rstd * gv.w + bv.w;
    ushort4 o;
    o.x = f2bf(n0); o.y = f2bf(n1); o.z = f2bf(n2); o.w = f2bf(n3);
    *(ushort4*)(out + (size_t)row * Dc + i) = o;
    // fused mag: dot normalized (bf16-rounded, matching GEMM operand) with Wm
    red[tid] = bf2f(o.x) * wv.x + bf2f(o.y) * wv.y + bf2f(o.z) * wv.z + bf2f(o.w) * wv.w;
    __syncthreads();
    for (int off = 128; off > 0; off >>= 1) {
        if (tid < off) red[tid] += red[tid + off];
        __syncthreads();
    }
    if (tid == 0) {
        float z = red[0] + bm[0];
        mag[row] = 1.f / (1.f + expf(-z));
    }
}

// ---------------------------------------------------------------------------
extern "C" void kernel_launch(void* const* d_in, const int* in_sizes, int n_in,
                              void* d_out, int out_size, void* d_ws, size_t ws_size,
                              hipStream_t stream) {
    const float* x     = (const float*)d_in[0];
    const float* query = (const float*)d_in[1];
    const float* Wk    = (const float*)d_in[2];
    const float* Wv    = (const float*)d_in[3];
    const float* Wt    = (const float*)d_in[4];
    const float* bt    = (const float*)d_in[5];
    const float* Wm    = (const float*)d_in[6];
    const float* bm    = (const float*)d_in[7];
    const float* ln_g  = (const float*)d_in[8];
    const float* ln_b  = (const float*)d_in[9];
    float* out = (float*)d_out;

    // workspace layout. NO ALIASING (G16 hazard, hit in R3).
    char* w = (char*)d_ws;
    auto alloc = [&](size_t bytes) { char* p = w; w += (bytes + 255) & ~(size_t)255; return p; };
    ushort* v        = (ushort*)alloc((size_t)Bc * Tc * Dc * 2);      // 16 MB
    ushort* pooled   = (ushort*)alloc((size_t)Bc * T2c * Dc * 2);     // 8 MB
    ushort* xb       = (ushort*)alloc((size_t)Bc * Tc * Dc * 2);      // 16 MB
    ushort* pooledn  = (ushort*)alloc((size_t)Bc * T2c * Dc * 2);     // 8 MB
    ushort* WvXT     = (ushort*)alloc((size_t)NEXT * Dc * 2);         // 2.25 MB
    ushort* WtT      = (ushort*)alloc((size_t)(Dc / 2) * Dc * 2);     // 1 MB
    float*  scores   = (float*) alloc((size_t)Bc * Hc * Tc * 4);      // 512 KB
    float*  chunkL   = (float*) alloc((size_t)Bc * Hc * NCc * 4);
    float*  chunkAcc = (float*) alloc((size_t)Bc * Hc * NCc * DHc * 4);

    // 1) fused prep: xb, WvXT (Wv + qk + pad), WtT
    k_prep<<<PREP_ZERO, 256, 0, stream>>>(x, Wv, Wt, Wk, query, xb, WvXT, WtT);
    // 2) v + scores: BM=128 BN=64 BK=64 swizzled-LDS MFMA; grid (64 row-tiles
    //    fastest, 17 col tiles: 0..15 v, 16 = scores) = 1088 blocks.
    k_gemm_v<<<dim3((Bc * Tc) / 128, 17), 256, 0, stream>>>(xb, WvXT, v, scores);
    // 3) chunk totals
    k_chunk<<<Bc * Hc * NCc, 64, 0, stream>>>(scores, v, chunkL, chunkAcc);
    // 4) emit (inline prefix)
    k_emit<<<Bc * Hc * NCc, 64, 0, stream>>>(scores, v, chunkL, chunkAcc, pooled);
    // 5) LayerNorm + mag
    k_lnmag<<<Bc * T2c, 256, 0, stream>>>(pooled, ln_g, ln_b, Wm, bm, pooledn,
                                          out + (size_t)Bc * T2c * (Dc / 2));
    // 6) theta = pooled_n @ Wt + bt  (4096 x 512 x 1024), BM=64 BN=64 BK=64
    k_gemm_t<<<dim3((Bc * T2c) / 64, (Dc / 2) / 64), 256, 0, stream>>>(
        pooledn, WtT, bt, out, Dc / 2, Dc);
}